// Round 13
// baseline (597.701 us; speedup 1.0000x reference)
//
#include <hip/hip_runtime.h>
#include <hip/hip_bf16.h>
#include <math.h>

#define HCW 512   // concat width H*C
#define NHD 8     // heads
#define CCH 64    // per-head channels

typedef unsigned short u16;
typedef unsigned int   u32;
typedef __attribute__((ext_vector_type(8))) short bf16x8;
typedef __attribute__((ext_vector_type(4))) float f32x4;

__device__ __forceinline__ float bf2f(u32 u) {
  union { float f; u32 i; } v; v.i = u << 16; return v.f;
}
__device__ __forceinline__ u16 f2bf(float f) {
  u32 x = __builtin_bit_cast(u32, f);
  return (u16)((x + 0x7fff + ((x >> 16) & 1)) >> 16);
}
__device__ __forceinline__ void gload_lds16(const void* g, void* l) {
  __builtin_amdgcn_global_load_lds(
      (const __attribute__((address_space(1))) u32*)g,
      (__attribute__((address_space(3))) u32*)l, 16, 0, 0);
}

// ---------------- CSR build (by dst), atomic-alloc ----------------
__global__ void k_hist(const int* __restrict__ ei, int* __restrict__ deg, int E, int N) {
  int e = blockIdx.x * blockDim.x + threadIdx.x;
  if (e >= E + N) return;
  int dst = (e < E) ? ei[E + e] : (e - E);
  atomicAdd(&deg[dst], 1);
}

// beg[] alloc + degree-bucket histogram
__global__ __launch_bounds__(256) void k_alloc(const int* __restrict__ deg, int* __restrict__ beg,
                                               int* __restrict__ cursor, int* __restrict__ dbin, int N) {
  int n = blockIdx.x * 256 + threadIdx.x;
  int lane = threadIdx.x & 63;
  int v = (n < N) ? deg[n] : 0;
  int incl = v;
  #pragma unroll
  for (int off = 1; off < 64; off <<= 1) {
    int t = __shfl_up(incl, off);
    if (lane >= off) incl += t;
  }
  int total = __shfl(incl, 63);
  int base = 0;
  if (lane == 63) base = atomicAdd(cursor, total);
  base = __shfl(base, 63);
  if (n < N) {
    beg[n] = base + incl - v;
    atomicAdd(&dbin[v < 63 ? v : 63], 1);
  }
}

__global__ void k_fill(const int* __restrict__ ei, const int* __restrict__ beg,
                       int* __restrict__ cnt, int* __restrict__ csr_src, int E, int N) {
  int e = blockIdx.x * blockDim.x + threadIdx.x;
  if (e >= E + N) return;
  int src, dst;
  if (e < E) { src = ei[e]; dst = ei[E + e]; } else { src = e - E; dst = e - E; }
  int pos = beg[dst] + atomicAdd(&cnt[dst], 1);
  csr_src[pos] = src;
}

// exclusive prefix over 64 degree buckets
__global__ __launch_bounds__(64) void k_dpre(const int* __restrict__ dbin, int* __restrict__ dbase) {
  int lane = threadIdx.x;
  int v = dbin[lane];
  int incl = v;
  #pragma unroll
  for (int off = 1; off < 64; off <<= 1) {
    int t = __shfl_up(incl, off);
    if (lane >= off) incl += t;
  }
  dbase[lane] = incl - v;
}

// scatter node ids into degree-sorted permutation
__global__ __launch_bounds__(256) void k_dscat(const int* __restrict__ deg, const int* __restrict__ dbase,
                                               int* __restrict__ dcnt, int* __restrict__ perm, int N) {
  int n = blockIdx.x * 256 + threadIdx.x;
  if (n >= N) return;
  int b = deg[n]; b = (b < 63) ? b : 63;
  int pos = dbase[b] + atomicAdd(&dcnt[b], 1);
  perm[pos] = n;
}

// ---------------- fused prep: W_gat^T, Wf, x->bf16, W_in^T ----------------
__global__ __launch_bounds__(256) void k_prep(const float* __restrict__ W_gat, u16* __restrict__ Wt,
                                              const float* __restrict__ W_h1, const float* __restrict__ W_att,
                                              u16* __restrict__ Wf,
                                              const float* __restrict__ x, u16* __restrict__ xb, int xtotal,
                                              const float* __restrict__ W_in, u16* __restrict__ Wtin,
                                              int XB) {
  __shared__ float sm[32][33];
  int b = blockIdx.x;
  int t = threadIdx.x;
  if (b < 768) {
    int l = b >> 8, rem = b & 255;
    int n0 = (rem & 15) * 32, k0 = (rem >> 4) * 32;
    const float* Wl = W_gat + (size_t)l * HCW * HCW;
    u16* Wtl = Wt + (size_t)l * HCW * HCW;
    int tx = t & 31, ty = t >> 5;
    #pragma unroll
    for (int r = 0; r < 32; r += 8)
      sm[ty + r][tx] = Wl[(size_t)(k0 + ty + r) * HCW + n0 + tx];
    __syncthreads();
    #pragma unroll
    for (int r = 0; r < 32; r += 8)
      Wtl[(size_t)(n0 + ty + r) * HCW + k0 + tx] = f2bf(sm[tx][ty + r]);
  } else if (b < 848) {
    int n = b - 768;
    for (int k = t; k < 512; k += 256) {
      float v = 0.f;
      if (n < 64) v = W_h1[(size_t)k * 64 + n];
      else if (n < 72) v = W_att[(size_t)k * 8 + (n - 64)];
      Wf[(size_t)n * 512 + k] = f2bf(v);
    }
  } else if (b < 848 + XB) {
    int i = ((b - 848) * 256 + t) * 8;
    if (i < xtotal) {
      float4 a = *(const float4*)(x + i);
      float4 bb = *(const float4*)(x + i + 4);
      uint4 o;
      o.x = (u32)f2bf(a.x) | ((u32)f2bf(a.y) << 16);
      o.y = (u32)f2bf(a.z) | ((u32)f2bf(a.w) << 16);
      o.z = (u32)f2bf(bb.x) | ((u32)f2bf(bb.y) << 16);
      o.w = (u32)f2bf(bb.z) | ((u32)f2bf(bb.w) << 16);
      *(uint4*)(xb + i) = o;
    }
  } else {
    int idx = (b - 848 - XB) * 256 + t;
    int n = idx >> 5, k = idx & 31;
    Wtin[idx] = f2bf(W_in[(size_t)k * HCW + n]);
  }
}

// ---------------- input projection via MFMA ----------------
__global__ __launch_bounds__(256) void k_inproj3(const u16* __restrict__ xb, const u16* __restrict__ Wt,
                                                 const float* __restrict__ b, u16* __restrict__ h, int N) {
  __shared__ u16 As[128 * 32];
  __shared__ u16 Bs[128 * 32];
  int tid = threadIdx.x, lane = tid & 63, w = tid >> 6;
  int bm = blockIdx.y * 128, bn = blockIdx.x * 128;
  #pragma unroll
  for (int it = 0; it < 4; it++) {
    int g = it * 256 + tid;
    if (g < 512) {
      int row = g >> 2, gb = g & 3, gs = gb ^ (row & 3);
      int ar = bm + row; if (ar >= N) ar = N - 1;
      gload_lds16(xb + (size_t)ar * 32 + gs * 8, &As[g * 8]);
    } else {
      int gg = g - 512;
      int row = gg >> 2, gb = gg & 3, gs = gb ^ (row & 3);
      gload_lds16(Wt + (size_t)(bn + row) * 32 + gs * 8, &Bs[gg * 8]);
    }
  }
  __syncthreads();
  bf16x8 af[2];
  #pragma unroll
  for (int i = 0; i < 2; i++) {
    int rowA = w * 32 + i * 16 + (lane & 15);
    int gA = (lane >> 4) ^ (rowA & 3);
    af[i] = *(const bf16x8*)&As[rowA * 32 + gA * 8];
  }
  f32x4 acc[2][8] = {};
  #pragma unroll
  for (int j = 0; j < 8; j++) {
    int rowB = j * 16 + (lane & 15);
    int gB = (lane >> 4) ^ (rowB & 3);
    bf16x8 bfr = *(const bf16x8*)&Bs[rowB * 32 + gB * 8];
    #pragma unroll
    for (int i = 0; i < 2; i++)
      acc[i][j] = __builtin_amdgcn_mfma_f32_16x16x32_bf16(af[i], bfr, acc[i][j], 0, 0, 0);
  }
  #pragma unroll
  for (int j = 0; j < 8; j++) {
    int col = bn + j * 16 + (lane & 15);
    float bb = b[col];
    #pragma unroll
    for (int i = 0; i < 2; i++) {
      #pragma unroll
      for (int r = 0; r < 4; r++) {
        int n = bm + w * 32 + i * 16 + (lane >> 4) * 4 + r;
        if (n < N) h[(size_t)n * HCW + col] = f2bf(fmaxf(acc[i][j][r] + bb, 0.f));
      }
    }
  }
}

// ---------------- bf16 MFMA GEMM + fused s/d epilogue, XCD-panel swizzle ----------------
__global__ __launch_bounds__(256) void k_gemm_mfma(const u16* __restrict__ A,
                                                   const u16* __restrict__ Bt,
                                                   u16* __restrict__ C,
                                                   const float* __restrict__ a_src,
                                                   const float* __restrict__ a_dst,
                                                   float* __restrict__ sarr,
                                                   float* __restrict__ darr,
                                                   int M) {
  int nPanels = (M + 127) >> 7;
  int lin = blockIdx.y * 4 + blockIdx.x;
  int xcd = lin & 7;
  int t = lin >> 3;
  int bn_i = t & 3;
  int p = t >> 2;
  int bm_i = p * 8 + xcd;
  if (bm_i >= nPanels) return;
  int bm = bm_i * 128, bn = bn_i * 128;

  __shared__ u16 As[128 * 64];
  __shared__ u16 Bs[128 * 64];
  int tid = threadIdx.x;
  int lane = tid & 63, w = tid >> 6;
  int wr = w >> 1, wc = w & 1;
  f32x4 acc[4][4] = {};
  for (int k0 = 0; k0 < 512; k0 += 64) {
    __syncthreads();
    #pragma unroll
    for (int it = 0; it < 4; it++) {
      int g = it * 256 + tid;
      int row = g >> 3;
      int gb = g & 7;
      int gs = gb ^ (row & 7);
      int ar = bm + row; if (ar >= M) ar = M - 1;
      gload_lds16(A + (size_t)ar * HCW + k0 + gs * 8, &As[g * 8]);
      gload_lds16(Bt + (size_t)(bn + row) * HCW + k0 + gs * 8, &Bs[g * 8]);
    }
    __syncthreads();
    #pragma unroll
    for (int ks = 0; ks < 2; ks++) {
      bf16x8 af[4], bfr[4];
      #pragma unroll
      for (int f = 0; f < 4; f++) {
        int rowA = wr * 64 + f * 16 + (lane & 15);
        int gA = ((ks * 4 + (lane >> 4)) ^ (rowA & 7));
        af[f] = *(const bf16x8*)&As[rowA * 64 + gA * 8];
        int rowB = wc * 64 + f * 16 + (lane & 15);
        int gB = ((ks * 4 + (lane >> 4)) ^ (rowB & 7));
        bfr[f] = *(const bf16x8*)&Bs[rowB * 64 + gB * 8];
      }
      #pragma unroll
      for (int i = 0; i < 4; i++)
        #pragma unroll
        for (int j = 0; j < 4; j++)
          acc[i][j] = __builtin_amdgcn_mfma_f32_16x16x32_bf16(af[i], bfr[j], acc[i][j], 0, 0, 0);
    }
  }
  int gr_base = bm + wr * 64;
  int gc_base = bn + wc * 64;
  #pragma unroll
  for (int i = 0; i < 4; i++) {
    #pragma unroll
    for (int j = 0; j < 4; j++) {
      int col = gc_base + j * 16 + (lane & 15);
      #pragma unroll
      for (int r = 0; r < 4; r++) {
        int rowg = gr_base + i * 16 + (lane >> 4) * 4 + r;
        if (rowg < M) C[(size_t)rowg * HCW + col] = f2bf(acc[i][j][r]);
      }
    }
  }
  int head = (bn >> 6) + wc;
  float asv[4], adv[4];
  #pragma unroll
  for (int j = 0; j < 4; j++) {
    asv[j] = a_src[head * 64 + j * 16 + (lane & 15)];
    adv[j] = a_dst[head * 64 + j * 16 + (lane & 15)];
  }
  #pragma unroll
  for (int i = 0; i < 4; i++) {
    #pragma unroll
    for (int r = 0; r < 4; r++) {
      float sv = acc[i][0][r] * asv[0] + acc[i][1][r] * asv[1]
               + acc[i][2][r] * asv[2] + acc[i][3][r] * asv[3];
      float dv = acc[i][0][r] * adv[0] + acc[i][1][r] * adv[1]
               + acc[i][2][r] * adv[2] + acc[i][3][r] * adv[3];
      sv += __shfl_xor(sv, 1); dv += __shfl_xor(dv, 1);
      sv += __shfl_xor(sv, 2); dv += __shfl_xor(dv, 2);
      sv += __shfl_xor(sv, 4); dv += __shfl_xor(dv, 4);
      sv += __shfl_xor(sv, 8); dv += __shfl_xor(dv, 8);
      if ((lane & 15) == 0) {
        int rowg = gr_base + i * 16 + (lane >> 4) * 4 + r;
        if (rowg < M) {
          sarr[(size_t)rowg * NHD + head] = sv;
          darr[(size_t)rowg * NHD + head] = dv;
        }
      }
    }
  }
}

// ---------------- channel-sliced softmax+agg v4: degree-sorted nodes via perm ----------------
// grid (8 heads, chunks): linear id % 8 == head -> XCD k only touches hp cols [k*64,k*64+64)
// (3.8 MB slice, L2-resident). Lane = (node-slot, channel-octet); nodes taken in degree-sorted
// order so all 8 node-slots of a wave have ~equal edge counts (kills max-vs-mean divergence).
__global__ __launch_bounds__(256) void k_agg11(const int* __restrict__ perm,
                                               const int* __restrict__ beg_, const int* __restrict__ deg_,
                                               const int* __restrict__ csr_src,
                                               const u16* __restrict__ hp, const float* __restrict__ s,
                                               const float* __restrict__ d, const float* __restrict__ bias,
                                               u16* __restrict__ hout, int N) {
  int hd = blockIdx.x;
  int wv = threadIdx.x >> 6, lane = threadIdx.x & 63;
  int nslot = lane >> 3;
  int q = lane & 7;
  int c = hd * 64 + q * 8;
  int gid = blockIdx.y * 32 + wv * 8 + nslot;
  if (gid >= N) return;
  int n = perm[gid];
  int beg = beg_[n], end = beg + deg_[n];
  float dn = d[(size_t)n * NHD + hd];
  const u16* hpc = hp + c;
  float acc[8] = {0.f, 0.f, 0.f, 0.f, 0.f, 0.f, 0.f, 0.f};
  float den = 0.f;

  int i = beg;
  for (; i + 2 <= end; i += 2) {
    int s0 = csr_src[i], s1 = csr_src[i + 1];
    float e0 = s[(size_t)s0 * NHD + hd] + dn;
    float e1 = s[(size_t)s1 * NHD + hd] + dn;
    uint4 v0 = *(const uint4*)(hpc + (size_t)s0 * HCW);
    uint4 v1 = *(const uint4*)(hpc + (size_t)s1 * HCW);
    e0 = (e0 > 0.f) ? e0 : 0.2f * e0;
    e1 = (e1 > 0.f) ? e1 : 0.2f * e1;
    float x0 = __expf(e0), x1 = __expf(e1);
    den += x0 + x1;
    u32 w0[4] = {v0.x, v0.y, v0.z, v0.w};
    u32 w1[4] = {v1.x, v1.y, v1.z, v1.w};
    #pragma unroll
    for (int j = 0; j < 4; j++) {
      acc[2 * j]     += x0 * bf2f(w0[j] & 0xffff) + x1 * bf2f(w1[j] & 0xffff);
      acc[2 * j + 1] += x0 * bf2f(w0[j] >> 16)    + x1 * bf2f(w1[j] >> 16);
    }
  }
  if (i < end) {
    int s0 = csr_src[i];
    float e0 = s[(size_t)s0 * NHD + hd] + dn;
    uint4 v0 = *(const uint4*)(hpc + (size_t)s0 * HCW);
    e0 = (e0 > 0.f) ? e0 : 0.2f * e0;
    float x0 = __expf(e0);
    den += x0;
    u32 w0[4] = {v0.x, v0.y, v0.z, v0.w};
    #pragma unroll
    for (int j = 0; j < 4; j++) {
      acc[2 * j]     += x0 * bf2f(w0[j] & 0xffff);
      acc[2 * j + 1] += x0 * bf2f(w0[j] >> 16);
    }
  }

  float inv = 1.f / (den + 1e-16f);
  float4 bv0 = *(const float4*)(bias + c);
  float4 bv1 = *(const float4*)(bias + c + 4);
  float bb[8] = {bv0.x, bv0.y, bv0.z, bv0.w, bv1.x, bv1.y, bv1.z, bv1.w};
  u32 out[4];
  #pragma unroll
  for (int j = 0; j < 4; j++) {
    float o0 = fmaxf(acc[2 * j] * inv + bb[2 * j], 0.f);
    float o1 = fmaxf(acc[2 * j + 1] * inv + bb[2 * j + 1], 0.f);
    out[j] = (u32)f2bf(o0) | ((u32)f2bf(o1) << 16);
  }
  *(uint4*)(hout + (size_t)n * HCW + c) = make_uint4(out[0], out[1], out[2], out[3]);
}

// ---------------- fused final heads via MFMA: [M,512] @ Wf^T[512,80] ----------------
__global__ __launch_bounds__(256) void k_final2(const u16* __restrict__ A,
                                                const u16* __restrict__ Wf,
                                                const float* __restrict__ b_att,
                                                const float* __restrict__ b_h1,
                                                const float* __restrict__ W_h2,
                                                const float* __restrict__ b_h2,
                                                float* __restrict__ anomaly, float* __restrict__ attw,
                                                int M) {
  __shared__ u16 As[128 * 64];
  __shared__ u16 Bs[80 * 64];
  __shared__ float so[4][32][84];
  int tid = threadIdx.x;
  int lane = tid & 63, w = tid >> 6;
  int bm = blockIdx.x * 128;
  f32x4 acc[2][5] = {};
  for (int k0 = 0; k0 < 512; k0 += 64) {
    __syncthreads();
    #pragma unroll
    for (int it = 0; it < 7; it++) {
      int g = it * 256 + tid;
      if (g < 1024) {
        int row = g >> 3, gb = g & 7;
        int gs = gb ^ (row & 7);
        int ar = bm + row; if (ar >= M) ar = M - 1;
        gload_lds16(A + (size_t)ar * HCW + k0 + gs * 8, &As[g * 8]);
      } else if (g < 1664) {
        int gg = g - 1024;
        int row = gg >> 3, gb = gg & 7;
        int gs = gb ^ (row & 7);
        gload_lds16(Wf + (size_t)row * 512 + k0 + gs * 8, &Bs[gg * 8]);
      }
    }
    __syncthreads();
    #pragma unroll
    for (int ks = 0; ks < 2; ks++) {
      bf16x8 af[2], bfr[5];
      #pragma unroll
      for (int i = 0; i < 2; i++) {
        int rowA = w * 32 + i * 16 + (lane & 15);
        int gA = ((ks * 4 + (lane >> 4)) ^ (rowA & 7));
        af[i] = *(const bf16x8*)&As[rowA * 64 + gA * 8];
      }
      #pragma unroll
      for (int j = 0; j < 5; j++) {
        int rowB = j * 16 + (lane & 15);
        int gB = ((ks * 4 + (lane >> 4)) ^ (rowB & 7));
        bfr[j] = *(const bf16x8*)&Bs[rowB * 64 + gB * 8];
      }
      #pragma unroll
      for (int i = 0; i < 2; i++)
        #pragma unroll
        for (int j = 0; j < 5; j++)
          acc[i][j] = __builtin_amdgcn_mfma_f32_16x16x32_bf16(af[i], bfr[j], acc[i][j], 0, 0, 0);
    }
  }
  #pragma unroll
  for (int i = 0; i < 2; i++) {
    #pragma unroll
    for (int j = 0; j < 5; j++) {
      int col = j * 16 + (lane & 15);
      #pragma unroll
      for (int r = 0; r < 4; r++) {
        int row_l = i * 16 + (lane >> 4) * 4 + r;
        so[w][row_l][col] = acc[i][j][r];
      }
    }
  }
  int row_l = lane >> 1, half = lane & 1;
  int n = bm + w * 32 + row_l;
  if (n < M) {
    float hacc = 0.f;
    #pragma unroll
    for (int kk = 0; kk < 32; kk++) {
      int cc = half * 32 + kk;
      float v = fmaxf(so[w][row_l][cc] + b_h1[cc], 0.f);
      hacc += v * W_h2[cc];
    }
    hacc += __shfl_xor(hacc, 1);
    if (half == 0) {
      anomaly[n] = 1.f / (1.f + __expf(-(hacc + b_h2[0])));
    } else {
      float lg[8];
      float mx = -1e30f;
      #pragma unroll
      for (int j = 0; j < 8; j++) {
        lg[j] = so[w][row_l][64 + j] + b_att[j];
        mx = fmaxf(mx, lg[j]);
      }
      float sum = 0.f;
      #pragma unroll
      for (int j = 0; j < 8; j++) { lg[j] = __expf(lg[j] - mx); sum += lg[j]; }
      float inv = 1.f / sum;
      #pragma unroll
      for (int j = 0; j < 8; j++) attw[(size_t)n * 8 + j] = lg[j] * inv;
    }
  }
}

extern "C" void kernel_launch(void* const* d_in, const int* in_sizes, int n_in,
                              void* d_out, int out_size, void* d_ws, size_t ws_size,
                              hipStream_t stream) {
  const float* x       = (const float*)d_in[0];
  const int*   ei      = (const int*)d_in[1];
  const float* W_in    = (const float*)d_in[2];
  const float* b_in    = (const float*)d_in[3];
  const float* W_gat   = (const float*)d_in[4];
  const float* att_src = (const float*)d_in[5];
  const float* att_dst = (const float*)d_in[6];
  const float* b_gat   = (const float*)d_in[7];
  const float* W_att   = (const float*)d_in[8];
  const float* b_att   = (const float*)d_in[9];
  const float* W_h1    = (const float*)d_in[10];
  const float* b_h1    = (const float*)d_in[11];
  const float* W_h2    = (const float*)d_in[12];
  const float* b_h2    = (const float*)d_in[13];

  const int N  = in_sizes[0] / 32;
  const int E  = in_sizes[1] / 2;
  const int ET = E + N;

  char* ws = (char*)d_ws;
  size_t off = 0;
  auto alloc = [&](size_t bytes) -> void* {
    void* p = ws + off;
    off = (off + bytes + 255) & ~(size_t)255;
    return p;
  };
  u16* h     = (u16*)alloc((size_t)N * HCW * 2);
  u16* hp    = (u16*)alloc((size_t)N * HCW * 2);
  u16* Wt    = (u16*)alloc((size_t)3 * HCW * HCW * 2);
  u16* Wf    = (u16*)alloc((size_t)80 * 512 * 2);
  u16* xb    = (u16*)alloc((size_t)N * 32 * 2);
  u16* Wtin  = (u16*)alloc((size_t)512 * 32 * 2);
  float* sarr = (float*)alloc((size_t)N * NHD * 4);
  float* darr = (float*)alloc((size_t)N * NHD * 4);
  int* zbuf   = (int*)alloc((size_t)(2 * N + 256) * 4);  // deg|cnt|cursor|dbin|dcnt
  int* deg    = zbuf;
  int* cnt    = zbuf + N;
  int* cursor = zbuf + 2 * N;
  int* dbin   = zbuf + 2 * N + 64;
  int* dcnt   = zbuf + 2 * N + 128;
  int* beg    = (int*)alloc((size_t)N * 4);
  int* dbase  = (int*)alloc((size_t)64 * 4);
  int* perm   = (int*)alloc((size_t)N * 4);
  int* csr    = (int*)alloc((size_t)ET * 4);

  float* anomaly = (float*)d_out;
  float* attw    = (float*)d_out + N;

  hipMemsetAsync(zbuf, 0, (size_t)(2 * N + 192) * 4, stream);

  int gbE = (ET + 255) / 256;
  int nb  = (N + 255) / 256;
  k_hist<<<gbE, 256, 0, stream>>>(ei, deg, E, N);
  k_alloc<<<nb, 256, 0, stream>>>(deg, beg, cursor, dbin, N);
  k_fill<<<gbE, 256, 0, stream>>>(ei, beg, cnt, csr, E, N);
  k_dpre<<<1, 64, 0, stream>>>(dbin, dbase);
  k_dscat<<<nb, 256, 0, stream>>>(deg, dbase, dcnt, perm, N);

  int xtotal = N * 32;
  int XB = (xtotal / 8 + 255) / 256;
  k_prep<<<848 + XB + 64, 256, 0, stream>>>(W_gat, Wt, W_h1, W_att, Wf, x, xb, xtotal,
                                            W_in, Wtin, XB);
  k_inproj3<<<dim3(4, (N + 127) / 128), 256, 0, stream>>>(xb, Wtin, b_in, h, N);

  int nPanels = (N + 127) / 128;
  int nPanelsPad = ((nPanels + 7) / 8) * 8;
  dim3 ggrid(4, nPanelsPad);
  dim3 agrid(8, (N + 31) / 32);
  for (int l = 0; l < 3; l++) {
    k_gemm_mfma<<<ggrid, 256, 0, stream>>>(h, Wt + (size_t)l * HCW * HCW, hp,
                                           att_src + (size_t)l * NHD * CCH,
                                           att_dst + (size_t)l * NHD * CCH,
                                           sarr, darr, N);
    k_agg11<<<agrid, 256, 0, stream>>>(perm, beg, deg, csr, hp, sarr, darr,
                                       b_gat + (size_t)l * HCW, h, N);
  }

  k_final2<<<(N + 127) / 128, 256, 0, stream>>>(h, Wf, b_att, b_h1, W_h2, b_h2,
                                                anomaly, attw, N);
}

// Round 14
// 438.120 us; speedup vs baseline: 1.3642x; 1.3642x over previous
//
#include <hip/hip_runtime.h>
#include <hip/hip_bf16.h>
#include <math.h>

#define HCW 512   // concat width H*C
#define NHD 8     // heads
#define CCH 64    // per-head channels

typedef unsigned short u16;
typedef unsigned int   u32;
typedef __attribute__((ext_vector_type(8))) short bf16x8;
typedef __attribute__((ext_vector_type(4))) float f32x4;

__device__ __forceinline__ float bf2f(u32 u) {
  union { float f; u32 i; } v; v.i = u << 16; return v.f;
}
__device__ __forceinline__ u16 f2bf(float f) {
  u32 x = __builtin_bit_cast(u32, f);
  return (u16)((x + 0x7fff + ((x >> 16) & 1)) >> 16);
}
__device__ __forceinline__ void gload_lds16(const void* g, void* l) {
  __builtin_amdgcn_global_load_lds(
      (const __attribute__((address_space(1))) u32*)g,
      (__attribute__((address_space(3))) u32*)l, 16, 0, 0);
}

// ---------------- CSR build (by dst), atomic-alloc ----------------
__global__ void k_hist(const int* __restrict__ ei, int* __restrict__ deg, int E, int N) {
  int e = blockIdx.x * blockDim.x + threadIdx.x;
  if (e >= E + N) return;
  int dst = (e < E) ? ei[E + e] : (e - E);
  atomicAdd(&deg[dst], 1);
}

// beg[] alloc + degree-bucket histogram (block-local LDS aggregation)
__global__ __launch_bounds__(256) void k_alloc(const int* __restrict__ deg, int* __restrict__ beg,
                                               int* __restrict__ cursor, int* __restrict__ dbin, int N) {
  __shared__ int lbin[64];
  int t = threadIdx.x;
  if (t < 64) lbin[t] = 0;
  __syncthreads();
  int n = blockIdx.x * 256 + t;
  int lane = t & 63;
  int v = (n < N) ? deg[n] : 0;
  int incl = v;
  #pragma unroll
  for (int off = 1; off < 64; off <<= 1) {
    int tt = __shfl_up(incl, off);
    if (lane >= off) incl += tt;
  }
  int total = __shfl(incl, 63);
  int base = 0;
  if (lane == 63) base = atomicAdd(cursor, total);
  base = __shfl(base, 63);
  if (n < N) {
    beg[n] = base + incl - v;
    int b = (v < 63) ? v : 63;
    atomicAdd(&lbin[b], 1);            // LDS atomic - cheap
  }
  __syncthreads();
  if (t < 64 && lbin[t] > 0) atomicAdd(&dbin[t], lbin[t]);
}

__global__ void k_fill(const int* __restrict__ ei, const int* __restrict__ beg,
                       int* __restrict__ cnt, int* __restrict__ csr_src, int E, int N) {
  int e = blockIdx.x * blockDim.x + threadIdx.x;
  if (e >= E + N) return;
  int src, dst;
  if (e < E) { src = ei[e]; dst = ei[E + e]; } else { src = e - E; dst = e - E; }
  int pos = beg[dst] + atomicAdd(&cnt[dst], 1);
  csr_src[pos] = src;
}

// exclusive prefix over 64 degree buckets
__global__ __launch_bounds__(64) void k_dpre(const int* __restrict__ dbin, int* __restrict__ dbase) {
  int lane = threadIdx.x;
  int v = dbin[lane];
  int incl = v;
  #pragma unroll
  for (int off = 1; off < 64; off <<= 1) {
    int t = __shfl_up(incl, off);
    if (lane >= off) incl += t;
  }
  dbase[lane] = incl - v;
}

// scatter node ids into degree-sorted permutation (block-local range reservation)
__global__ __launch_bounds__(256) void k_dscat(const int* __restrict__ deg, const int* __restrict__ dbase,
                                               int* __restrict__ dcnt, int* __restrict__ perm, int N) {
  __shared__ int lcnt[64];
  __shared__ int lbase[64];
  int t = threadIdx.x;
  if (t < 64) lcnt[t] = 0;
  __syncthreads();
  int n = blockIdx.x * 256 + t;
  int b = 0, lrank = 0;
  if (n < N) {
    int v = deg[n];
    b = (v < 63) ? v : 63;
    lrank = atomicAdd(&lcnt[b], 1);    // LDS atomic
  }
  __syncthreads();
  if (t < 64) lbase[t] = (lcnt[t] > 0) ? atomicAdd(&dcnt[t], lcnt[t]) : 0;
  __syncthreads();
  if (n < N) perm[dbase[b] + lbase[b] + lrank] = n;
}

// ---------------- fused prep: W_gat^T, Wf, x->bf16, W_in^T ----------------
__global__ __launch_bounds__(256) void k_prep(const float* __restrict__ W_gat, u16* __restrict__ Wt,
                                              const float* __restrict__ W_h1, const float* __restrict__ W_att,
                                              u16* __restrict__ Wf,
                                              const float* __restrict__ x, u16* __restrict__ xb, int xtotal,
                                              const float* __restrict__ W_in, u16* __restrict__ Wtin,
                                              int XB) {
  __shared__ float sm[32][33];
  int b = blockIdx.x;
  int t = threadIdx.x;
  if (b < 768) {
    int l = b >> 8, rem = b & 255;
    int n0 = (rem & 15) * 32, k0 = (rem >> 4) * 32;
    const float* Wl = W_gat + (size_t)l * HCW * HCW;
    u16* Wtl = Wt + (size_t)l * HCW * HCW;
    int tx = t & 31, ty = t >> 5;
    #pragma unroll
    for (int r = 0; r < 32; r += 8)
      sm[ty + r][tx] = Wl[(size_t)(k0 + ty + r) * HCW + n0 + tx];
    __syncthreads();
    #pragma unroll
    for (int r = 0; r < 32; r += 8)
      Wtl[(size_t)(n0 + ty + r) * HCW + k0 + tx] = f2bf(sm[tx][ty + r]);
  } else if (b < 848) {
    int n = b - 768;
    for (int k = t; k < 512; k += 256) {
      float v = 0.f;
      if (n < 64) v = W_h1[(size_t)k * 64 + n];
      else if (n < 72) v = W_att[(size_t)k * 8 + (n - 64)];
      Wf[(size_t)n * 512 + k] = f2bf(v);
    }
  } else if (b < 848 + XB) {
    int i = ((b - 848) * 256 + t) * 8;
    if (i < xtotal) {
      float4 a = *(const float4*)(x + i);
      float4 bb = *(const float4*)(x + i + 4);
      uint4 o;
      o.x = (u32)f2bf(a.x) | ((u32)f2bf(a.y) << 16);
      o.y = (u32)f2bf(a.z) | ((u32)f2bf(a.w) << 16);
      o.z = (u32)f2bf(bb.x) | ((u32)f2bf(bb.y) << 16);
      o.w = (u32)f2bf(bb.z) | ((u32)f2bf(bb.w) << 16);
      *(uint4*)(xb + i) = o;
    }
  } else {
    int idx = (b - 848 - XB) * 256 + t;
    int n = idx >> 5, k = idx & 31;
    Wtin[idx] = f2bf(W_in[(size_t)k * HCW + n]);
  }
}

// ---------------- input projection via MFMA ----------------
__global__ __launch_bounds__(256) void k_inproj3(const u16* __restrict__ xb, const u16* __restrict__ Wt,
                                                 const float* __restrict__ b, u16* __restrict__ h, int N) {
  __shared__ u16 As[128 * 32];
  __shared__ u16 Bs[128 * 32];
  int tid = threadIdx.x, lane = tid & 63, w = tid >> 6;
  int bm = blockIdx.y * 128, bn = blockIdx.x * 128;
  #pragma unroll
  for (int it = 0; it < 4; it++) {
    int g = it * 256 + tid;
    if (g < 512) {
      int row = g >> 2, gb = g & 3, gs = gb ^ (row & 3);
      int ar = bm + row; if (ar >= N) ar = N - 1;
      gload_lds16(xb + (size_t)ar * 32 + gs * 8, &As[g * 8]);
    } else {
      int gg = g - 512;
      int row = gg >> 2, gb = gg & 3, gs = gb ^ (row & 3);
      gload_lds16(Wt + (size_t)(bn + row) * 32 + gs * 8, &Bs[gg * 8]);
    }
  }
  __syncthreads();
  bf16x8 af[2];
  #pragma unroll
  for (int i = 0; i < 2; i++) {
    int rowA = w * 32 + i * 16 + (lane & 15);
    int gA = (lane >> 4) ^ (rowA & 3);
    af[i] = *(const bf16x8*)&As[rowA * 32 + gA * 8];
  }
  f32x4 acc[2][8] = {};
  #pragma unroll
  for (int j = 0; j < 8; j++) {
    int rowB = j * 16 + (lane & 15);
    int gB = (lane >> 4) ^ (rowB & 3);
    bf16x8 bfr = *(const bf16x8*)&Bs[rowB * 32 + gB * 8];
    #pragma unroll
    for (int i = 0; i < 2; i++)
      acc[i][j] = __builtin_amdgcn_mfma_f32_16x16x32_bf16(af[i], bfr, acc[i][j], 0, 0, 0);
  }
  #pragma unroll
  for (int j = 0; j < 8; j++) {
    int col = bn + j * 16 + (lane & 15);
    float bb = b[col];
    #pragma unroll
    for (int i = 0; i < 2; i++) {
      #pragma unroll
      for (int r = 0; r < 4; r++) {
        int n = bm + w * 32 + i * 16 + (lane >> 4) * 4 + r;
        if (n < N) h[(size_t)n * HCW + col] = f2bf(fmaxf(acc[i][j][r] + bb, 0.f));
      }
    }
  }
}

// ---------------- bf16 MFMA GEMM + fused s/d epilogue, XCD-panel swizzle ----------------
__global__ __launch_bounds__(256) void k_gemm_mfma(const u16* __restrict__ A,
                                                   const u16* __restrict__ Bt,
                                                   u16* __restrict__ C,
                                                   const float* __restrict__ a_src,
                                                   const float* __restrict__ a_dst,
                                                   float* __restrict__ sarr,
                                                   float* __restrict__ darr,
                                                   int M) {
  int nPanels = (M + 127) >> 7;
  int lin = blockIdx.y * 4 + blockIdx.x;
  int xcd = lin & 7;
  int t = lin >> 3;
  int bn_i = t & 3;
  int p = t >> 2;
  int bm_i = p * 8 + xcd;
  if (bm_i >= nPanels) return;
  int bm = bm_i * 128, bn = bn_i * 128;

  __shared__ u16 As[128 * 64];
  __shared__ u16 Bs[128 * 64];
  int tid = threadIdx.x;
  int lane = tid & 63, w = tid >> 6;
  int wr = w >> 1, wc = w & 1;
  f32x4 acc[4][4] = {};
  for (int k0 = 0; k0 < 512; k0 += 64) {
    __syncthreads();
    #pragma unroll
    for (int it = 0; it < 4; it++) {
      int g = it * 256 + tid;
      int row = g >> 3;
      int gb = g & 7;
      int gs = gb ^ (row & 7);
      int ar = bm + row; if (ar >= M) ar = M - 1;
      gload_lds16(A + (size_t)ar * HCW + k0 + gs * 8, &As[g * 8]);
      gload_lds16(Bt + (size_t)(bn + row) * HCW + k0 + gs * 8, &Bs[g * 8]);
    }
    __syncthreads();
    #pragma unroll
    for (int ks = 0; ks < 2; ks++) {
      bf16x8 af[4], bfr[4];
      #pragma unroll
      for (int f = 0; f < 4; f++) {
        int rowA = wr * 64 + f * 16 + (lane & 15);
        int gA = ((ks * 4 + (lane >> 4)) ^ (rowA & 7));
        af[f] = *(const bf16x8*)&As[rowA * 64 + gA * 8];
        int rowB = wc * 64 + f * 16 + (lane & 15);
        int gB = ((ks * 4 + (lane >> 4)) ^ (rowB & 7));
        bfr[f] = *(const bf16x8*)&Bs[rowB * 64 + gB * 8];
      }
      #pragma unroll
      for (int i = 0; i < 4; i++)
        #pragma unroll
        for (int j = 0; j < 4; j++)
          acc[i][j] = __builtin_amdgcn_mfma_f32_16x16x32_bf16(af[i], bfr[j], acc[i][j], 0, 0, 0);
    }
  }
  int gr_base = bm + wr * 64;
  int gc_base = bn + wc * 64;
  #pragma unroll
  for (int i = 0; i < 4; i++) {
    #pragma unroll
    for (int j = 0; j < 4; j++) {
      int col = gc_base + j * 16 + (lane & 15);
      #pragma unroll
      for (int r = 0; r < 4; r++) {
        int rowg = gr_base + i * 16 + (lane >> 4) * 4 + r;
        if (rowg < M) C[(size_t)rowg * HCW + col] = f2bf(acc[i][j][r]);
      }
    }
  }
  int head = (bn >> 6) + wc;
  float asv[4], adv[4];
  #pragma unroll
  for (int j = 0; j < 4; j++) {
    asv[j] = a_src[head * 64 + j * 16 + (lane & 15)];
    adv[j] = a_dst[head * 64 + j * 16 + (lane & 15)];
  }
  #pragma unroll
  for (int i = 0; i < 4; i++) {
    #pragma unroll
    for (int r = 0; r < 4; r++) {
      float sv = acc[i][0][r] * asv[0] + acc[i][1][r] * asv[1]
               + acc[i][2][r] * asv[2] + acc[i][3][r] * asv[3];
      float dv = acc[i][0][r] * adv[0] + acc[i][1][r] * adv[1]
               + acc[i][2][r] * adv[2] + acc[i][3][r] * adv[3];
      sv += __shfl_xor(sv, 1); dv += __shfl_xor(dv, 1);
      sv += __shfl_xor(sv, 2); dv += __shfl_xor(dv, 2);
      sv += __shfl_xor(sv, 4); dv += __shfl_xor(dv, 4);
      sv += __shfl_xor(sv, 8); dv += __shfl_xor(dv, 8);
      if ((lane & 15) == 0) {
        int rowg = gr_base + i * 16 + (lane >> 4) * 4 + r;
        if (rowg < M) {
          sarr[(size_t)rowg * NHD + head] = sv;
          darr[(size_t)rowg * NHD + head] = dv;
        }
      }
    }
  }
}

// ---------------- channel-sliced softmax+agg v4: degree-sorted nodes via perm ----------------
__global__ __launch_bounds__(256) void k_agg11(const int* __restrict__ perm,
                                               const int* __restrict__ beg_, const int* __restrict__ deg_,
                                               const int* __restrict__ csr_src,
                                               const u16* __restrict__ hp, const float* __restrict__ s,
                                               const float* __restrict__ d, const float* __restrict__ bias,
                                               u16* __restrict__ hout, int N) {
  int hd = blockIdx.x;
  int wv = threadIdx.x >> 6, lane = threadIdx.x & 63;
  int nslot = lane >> 3;
  int q = lane & 7;
  int c = hd * 64 + q * 8;
  int gid = blockIdx.y * 32 + wv * 8 + nslot;
  if (gid >= N) return;
  int n = perm[gid];
  int beg = beg_[n], end = beg + deg_[n];
  float dn = d[(size_t)n * NHD + hd];
  const u16* hpc = hp + c;
  float acc[8] = {0.f, 0.f, 0.f, 0.f, 0.f, 0.f, 0.f, 0.f};
  float den = 0.f;

  int i = beg;
  for (; i + 2 <= end; i += 2) {
    int s0 = csr_src[i], s1 = csr_src[i + 1];
    float e0 = s[(size_t)s0 * NHD + hd] + dn;
    float e1 = s[(size_t)s1 * NHD + hd] + dn;
    uint4 v0 = *(const uint4*)(hpc + (size_t)s0 * HCW);
    uint4 v1 = *(const uint4*)(hpc + (size_t)s1 * HCW);
    e0 = (e0 > 0.f) ? e0 : 0.2f * e0;
    e1 = (e1 > 0.f) ? e1 : 0.2f * e1;
    float x0 = __expf(e0), x1 = __expf(e1);
    den += x0 + x1;
    u32 w0[4] = {v0.x, v0.y, v0.z, v0.w};
    u32 w1[4] = {v1.x, v1.y, v1.z, v1.w};
    #pragma unroll
    for (int j = 0; j < 4; j++) {
      acc[2 * j]     += x0 * bf2f(w0[j] & 0xffff) + x1 * bf2f(w1[j] & 0xffff);
      acc[2 * j + 1] += x0 * bf2f(w0[j] >> 16)    + x1 * bf2f(w1[j] >> 16);
    }
  }
  if (i < end) {
    int s0 = csr_src[i];
    float e0 = s[(size_t)s0 * NHD + hd] + dn;
    uint4 v0 = *(const uint4*)(hpc + (size_t)s0 * HCW);
    e0 = (e0 > 0.f) ? e0 : 0.2f * e0;
    float x0 = __expf(e0);
    den += x0;
    u32 w0[4] = {v0.x, v0.y, v0.z, v0.w};
    #pragma unroll
    for (int j = 0; j < 4; j++) {
      acc[2 * j]     += x0 * bf2f(w0[j] & 0xffff);
      acc[2 * j + 1] += x0 * bf2f(w0[j] >> 16);
    }
  }

  float inv = 1.f / (den + 1e-16f);
  float4 bv0 = *(const float4*)(bias + c);
  float4 bv1 = *(const float4*)(bias + c + 4);
  float bb[8] = {bv0.x, bv0.y, bv0.z, bv0.w, bv1.x, bv1.y, bv1.z, bv1.w};
  u32 out[4];
  #pragma unroll
  for (int j = 0; j < 4; j++) {
    float o0 = fmaxf(acc[2 * j] * inv + bb[2 * j], 0.f);
    float o1 = fmaxf(acc[2 * j + 1] * inv + bb[2 * j + 1], 0.f);
    out[j] = (u32)f2bf(o0) | ((u32)f2bf(o1) << 16);
  }
  *(uint4*)(hout + (size_t)n * HCW + c) = make_uint4(out[0], out[1], out[2], out[3]);
}

// ---------------- fused final heads via MFMA: [M,512] @ Wf^T[512,80] ----------------
__global__ __launch_bounds__(256) void k_final2(const u16* __restrict__ A,
                                                const u16* __restrict__ Wf,
                                                const float* __restrict__ b_att,
                                                const float* __restrict__ b_h1,
                                                const float* __restrict__ W_h2,
                                                const float* __restrict__ b_h2,
                                                float* __restrict__ anomaly, float* __restrict__ attw,
                                                int M) {
  __shared__ u16 As[128 * 64];
  __shared__ u16 Bs[80 * 64];
  __shared__ float so[4][32][84];
  int tid = threadIdx.x;
  int lane = tid & 63, w = tid >> 6;
  int bm = blockIdx.x * 128;
  f32x4 acc[2][5] = {};
  for (int k0 = 0; k0 < 512; k0 += 64) {
    __syncthreads();
    #pragma unroll
    for (int it = 0; it < 7; it++) {
      int g = it * 256 + tid;
      if (g < 1024) {
        int row = g >> 3, gb = g & 7;
        int gs = gb ^ (row & 7);
        int ar = bm + row; if (ar >= M) ar = M - 1;
        gload_lds16(A + (size_t)ar * HCW + k0 + gs * 8, &As[g * 8]);
      } else if (g < 1664) {
        int gg = g - 1024;
        int row = gg >> 3, gb = gg & 7;
        int gs = gb ^ (row & 7);
        gload_lds16(Wf + (size_t)row * 512 + k0 + gs * 8, &Bs[gg * 8]);
      }
    }
    __syncthreads();
    #pragma unroll
    for (int ks = 0; ks < 2; ks++) {
      bf16x8 af[2], bfr[5];
      #pragma unroll
      for (int i = 0; i < 2; i++) {
        int rowA = w * 32 + i * 16 + (lane & 15);
        int gA = ((ks * 4 + (lane >> 4)) ^ (rowA & 7));
        af[i] = *(const bf16x8*)&As[rowA * 64 + gA * 8];
      }
      #pragma unroll
      for (int j = 0; j < 5; j++) {
        int rowB = j * 16 + (lane & 15);
        int gB = ((ks * 4 + (lane >> 4)) ^ (rowB & 7));
        bfr[j] = *(const bf16x8*)&Bs[rowB * 64 + gB * 8];
      }
      #pragma unroll
      for (int i = 0; i < 2; i++)
        #pragma unroll
        for (int j = 0; j < 5; j++)
          acc[i][j] = __builtin_amdgcn_mfma_f32_16x16x32_bf16(af[i], bfr[j], acc[i][j], 0, 0, 0);
    }
  }
  #pragma unroll
  for (int i = 0; i < 2; i++) {
    #pragma unroll
    for (int j = 0; j < 5; j++) {
      int col = j * 16 + (lane & 15);
      #pragma unroll
      for (int r = 0; r < 4; r++) {
        int row_l = i * 16 + (lane >> 4) * 4 + r;
        so[w][row_l][col] = acc[i][j][r];
      }
    }
  }
  int row_l = lane >> 1, half = lane & 1;
  int n = bm + w * 32 + row_l;
  if (n < M) {
    float hacc = 0.f;
    #pragma unroll
    for (int kk = 0; kk < 32; kk++) {
      int cc = half * 32 + kk;
      float v = fmaxf(so[w][row_l][cc] + b_h1[cc], 0.f);
      hacc += v * W_h2[cc];
    }
    hacc += __shfl_xor(hacc, 1);
    if (half == 0) {
      anomaly[n] = 1.f / (1.f + __expf(-(hacc + b_h2[0])));
    } else {
      float lg[8];
      float mx = -1e30f;
      #pragma unroll
      for (int j = 0; j < 8; j++) {
        lg[j] = so[w][row_l][64 + j] + b_att[j];
        mx = fmaxf(mx, lg[j]);
      }
      float sum = 0.f;
      #pragma unroll
      for (int j = 0; j < 8; j++) { lg[j] = __expf(lg[j] - mx); sum += lg[j]; }
      float inv = 1.f / sum;
      #pragma unroll
      for (int j = 0; j < 8; j++) attw[(size_t)n * 8 + j] = lg[j] * inv;
    }
  }
}

extern "C" void kernel_launch(void* const* d_in, const int* in_sizes, int n_in,
                              void* d_out, int out_size, void* d_ws, size_t ws_size,
                              hipStream_t stream) {
  const float* x       = (const float*)d_in[0];
  const int*   ei      = (const int*)d_in[1];
  const float* W_in    = (const float*)d_in[2];
  const float* b_in    = (const float*)d_in[3];
  const float* W_gat   = (const float*)d_in[4];
  const float* att_src = (const float*)d_in[5];
  const float* att_dst = (const float*)d_in[6];
  const float* b_gat   = (const float*)d_in[7];
  const float* W_att   = (const float*)d_in[8];
  const float* b_att   = (const float*)d_in[9];
  const float* W_h1    = (const float*)d_in[10];
  const float* b_h1    = (const float*)d_in[11];
  const float* W_h2    = (const float*)d_in[12];
  const float* b_h2    = (const float*)d_in[13];

  const int N  = in_sizes[0] / 32;
  const int E  = in_sizes[1] / 2;
  const int ET = E + N;

  char* ws = (char*)d_ws;
  size_t off = 0;
  auto alloc = [&](size_t bytes) -> void* {
    void* p = ws + off;
    off = (off + bytes + 255) & ~(size_t)255;
    return p;
  };
  u16* h     = (u16*)alloc((size_t)N * HCW * 2);
  u16* hp    = (u16*)alloc((size_t)N * HCW * 2);
  u16* Wt    = (u16*)alloc((size_t)3 * HCW * HCW * 2);
  u16* Wf    = (u16*)alloc((size_t)80 * 512 * 2);
  u16* xb    = (u16*)alloc((size_t)N * 32 * 2);
  u16* Wtin  = (u16*)alloc((size_t)512 * 32 * 2);
  float* sarr = (float*)alloc((size_t)N * NHD * 4);
  float* darr = (float*)alloc((size_t)N * NHD * 4);
  int* zbuf   = (int*)alloc((size_t)(2 * N + 256) * 4);  // deg|cnt|cursor|dbin|dcnt
  int* deg    = zbuf;
  int* cnt    = zbuf + N;
  int* cursor = zbuf + 2 * N;
  int* dbin   = zbuf + 2 * N + 64;
  int* dcnt   = zbuf + 2 * N + 128;
  int* beg    = (int*)alloc((size_t)N * 4);
  int* dbase  = (int*)alloc((size_t)64 * 4);
  int* perm   = (int*)alloc((size_t)N * 4);
  int* csr    = (int*)alloc((size_t)ET * 4);

  float* anomaly = (float*)d_out;
  float* attw    = (float*)d_out + N;

  hipMemsetAsync(zbuf, 0, (size_t)(2 * N + 192) * 4, stream);

  int gbE = (ET + 255) / 256;
  int nb  = (N + 255) / 256;
  k_hist<<<gbE, 256, 0, stream>>>(ei, deg, E, N);
  k_alloc<<<nb, 256, 0, stream>>>(deg, beg, cursor, dbin, N);
  k_fill<<<gbE, 256, 0, stream>>>(ei, beg, cnt, csr, E, N);
  k_dpre<<<1, 64, 0, stream>>>(dbin, dbase);
  k_dscat<<<nb, 256, 0, stream>>>(deg, dbase, dcnt, perm, N);

  int xtotal = N * 32;
  int XB = (xtotal / 8 + 255) / 256;
  k_prep<<<848 + XB + 64, 256, 0, stream>>>(W_gat, Wt, W_h1, W_att, Wf, x, xb, xtotal,
                                            W_in, Wtin, XB);
  k_inproj3<<<dim3(4, (N + 127) / 128), 256, 0, stream>>>(xb, Wtin, b_in, h, N);

  int nPanels = (N + 127) / 128;
  int nPanelsPad = ((nPanels + 7) / 8) * 8;
  dim3 ggrid(4, nPanelsPad);
  dim3 agrid(8, (N + 31) / 32);
  for (int l = 0; l < 3; l++) {
    k_gemm_mfma<<<ggrid, 256, 0, stream>>>(h, Wt + (size_t)l * HCW * HCW, hp,
                                           att_src + (size_t)l * NHD * CCH,
                                           att_dst + (size_t)l * NHD * CCH,
                                           sarr, darr, N);
    k_agg11<<<agrid, 256, 0, stream>>>(perm, beg, deg, csr, hp, sarr, darr,
                                       b_gat + (size_t)l * HCW, h, N);
  }

  k_final2<<<(N + 127) / 128, 256, 0, stream>>>(h, Wf, b_att, b_h1, W_h2, b_h2,
                                                anomaly, attw, N);
}

// Round 15
// 424.206 us; speedup vs baseline: 1.4090x; 1.0328x over previous
//
#include <hip/hip_runtime.h>
#include <hip/hip_bf16.h>
#include <math.h>

#define HCW 512   // concat width H*C
#define NHD 8     // heads
#define CCH 64    // per-head channels

typedef unsigned short u16;
typedef unsigned int   u32;
typedef __attribute__((ext_vector_type(8))) short bf16x8;
typedef __attribute__((ext_vector_type(4))) float f32x4;

__device__ __forceinline__ float bf2f(u32 u) {
  union { float f; u32 i; } v; v.i = u << 16; return v.f;
}
__device__ __forceinline__ u16 f2bf(float f) {
  u32 x = __builtin_bit_cast(u32, f);
  return (u16)((x + 0x7fff + ((x >> 16) & 1)) >> 16);
}
__device__ __forceinline__ void gload_lds16(const void* g, void* l) {
  __builtin_amdgcn_global_load_lds(
      (const __attribute__((address_space(1))) u32*)g,
      (__attribute__((address_space(3))) u32*)l, 16, 0, 0);
}

// ---------------- CSR build (by dst), atomic-alloc ----------------
__global__ void k_hist(const int* __restrict__ ei, int* __restrict__ deg, int E, int N) {
  int e = blockIdx.x * blockDim.x + threadIdx.x;
  if (e >= E + N) return;
  int dst = (e < E) ? ei[E + e] : (e - E);
  atomicAdd(&deg[dst], 1);
}

__global__ __launch_bounds__(256) void k_alloc(const int* __restrict__ deg, int* __restrict__ beg,
                                               int* __restrict__ cursor, int N) {
  int n = blockIdx.x * 256 + threadIdx.x;
  int lane = threadIdx.x & 63;
  int v = (n < N) ? deg[n] : 0;
  int incl = v;
  #pragma unroll
  for (int off = 1; off < 64; off <<= 1) {
    int t = __shfl_up(incl, off);
    if (lane >= off) incl += t;
  }
  int total = __shfl(incl, 63);
  int base = 0;
  if (lane == 63) base = atomicAdd(cursor, total);
  base = __shfl(base, 63);
  if (n < N) beg[n] = base + incl - v;
}

__global__ void k_fill(const int* __restrict__ ei, const int* __restrict__ beg,
                       int* __restrict__ cnt, int* __restrict__ csr_src, int E, int N) {
  int e = blockIdx.x * blockDim.x + threadIdx.x;
  if (e >= E + N) return;
  int src, dst;
  if (e < E) { src = ei[e]; dst = ei[E + e]; } else { src = e - E; dst = e - E; }
  int pos = beg[dst] + atomicAdd(&cnt[dst], 1);
  csr_src[pos] = src;
}

// ---------------- fused prep: W_gat^T, Wf, x->bf16, W_in^T ----------------
__global__ __launch_bounds__(256) void k_prep(const float* __restrict__ W_gat, u16* __restrict__ Wt,
                                              const float* __restrict__ W_h1, const float* __restrict__ W_att,
                                              u16* __restrict__ Wf,
                                              const float* __restrict__ x, u16* __restrict__ xb, int xtotal,
                                              const float* __restrict__ W_in, u16* __restrict__ Wtin,
                                              int XB) {
  __shared__ float sm[32][33];
  int b = blockIdx.x;
  int t = threadIdx.x;
  if (b < 768) {
    int l = b >> 8, rem = b & 255;
    int n0 = (rem & 15) * 32, k0 = (rem >> 4) * 32;
    const float* Wl = W_gat + (size_t)l * HCW * HCW;
    u16* Wtl = Wt + (size_t)l * HCW * HCW;
    int tx = t & 31, ty = t >> 5;
    #pragma unroll
    for (int r = 0; r < 32; r += 8)
      sm[ty + r][tx] = Wl[(size_t)(k0 + ty + r) * HCW + n0 + tx];
    __syncthreads();
    #pragma unroll
    for (int r = 0; r < 32; r += 8)
      Wtl[(size_t)(n0 + ty + r) * HCW + k0 + tx] = f2bf(sm[tx][ty + r]);
  } else if (b < 848) {
    int n = b - 768;
    for (int k = t; k < 512; k += 256) {
      float v = 0.f;
      if (n < 64) v = W_h1[(size_t)k * 64 + n];
      else if (n < 72) v = W_att[(size_t)k * 8 + (n - 64)];
      Wf[(size_t)n * 512 + k] = f2bf(v);
    }
  } else if (b < 848 + XB) {
    int i = ((b - 848) * 256 + t) * 8;
    if (i < xtotal) {
      float4 a = *(const float4*)(x + i);
      float4 bb = *(const float4*)(x + i + 4);
      uint4 o;
      o.x = (u32)f2bf(a.x) | ((u32)f2bf(a.y) << 16);
      o.y = (u32)f2bf(a.z) | ((u32)f2bf(a.w) << 16);
      o.z = (u32)f2bf(bb.x) | ((u32)f2bf(bb.y) << 16);
      o.w = (u32)f2bf(bb.z) | ((u32)f2bf(bb.w) << 16);
      *(uint4*)(xb + i) = o;
    }
  } else {
    int idx = (b - 848 - XB) * 256 + t;
    int n = idx >> 5, k = idx & 31;
    Wtin[idx] = f2bf(W_in[(size_t)k * HCW + n]);
  }
}

// ---------------- input projection via MFMA ----------------
__global__ __launch_bounds__(256) void k_inproj3(const u16* __restrict__ xb, const u16* __restrict__ Wt,
                                                 const float* __restrict__ b, u16* __restrict__ h, int N) {
  __shared__ u16 As[128 * 32];
  __shared__ u16 Bs[128 * 32];
  int tid = threadIdx.x, lane = tid & 63, w = tid >> 6;
  int bm = blockIdx.y * 128, bn = blockIdx.x * 128;
  #pragma unroll
  for (int it = 0; it < 4; it++) {
    int g = it * 256 + tid;
    if (g < 512) {
      int row = g >> 2, gb = g & 3, gs = gb ^ (row & 3);
      int ar = bm + row; if (ar >= N) ar = N - 1;
      gload_lds16(xb + (size_t)ar * 32 + gs * 8, &As[g * 8]);
    } else {
      int gg = g - 512;
      int row = gg >> 2, gb = gg & 3, gs = gb ^ (row & 3);
      gload_lds16(Wt + (size_t)(bn + row) * 32 + gs * 8, &Bs[gg * 8]);
    }
  }
  __syncthreads();
  bf16x8 af[2];
  #pragma unroll
  for (int i = 0; i < 2; i++) {
    int rowA = w * 32 + i * 16 + (lane & 15);
    int gA = (lane >> 4) ^ (rowA & 3);
    af[i] = *(const bf16x8*)&As[rowA * 32 + gA * 8];
  }
  f32x4 acc[2][8] = {};
  #pragma unroll
  for (int j = 0; j < 8; j++) {
    int rowB = j * 16 + (lane & 15);
    int gB = (lane >> 4) ^ (rowB & 3);
    bf16x8 bfr = *(const bf16x8*)&Bs[rowB * 32 + gB * 8];
    #pragma unroll
    for (int i = 0; i < 2; i++)
      acc[i][j] = __builtin_amdgcn_mfma_f32_16x16x32_bf16(af[i], bfr, acc[i][j], 0, 0, 0);
  }
  #pragma unroll
  for (int j = 0; j < 8; j++) {
    int col = bn + j * 16 + (lane & 15);
    float bb = b[col];
    #pragma unroll
    for (int i = 0; i < 2; i++) {
      #pragma unroll
      for (int r = 0; r < 4; r++) {
        int n = bm + w * 32 + i * 16 + (lane >> 4) * 4 + r;
        if (n < N) h[(size_t)n * HCW + col] = f2bf(fmaxf(acc[i][j][r] + bb, 0.f));
      }
    }
  }
}

// ---------------- bf16 MFMA GEMM, double-buffered BK=32, + fused s/d epilogue ----------------
__global__ __launch_bounds__(256) void k_gemm_mfma(const u16* __restrict__ A,
                                                   const u16* __restrict__ Bt,
                                                   u16* __restrict__ C,
                                                   const float* __restrict__ a_src,
                                                   const float* __restrict__ a_dst,
                                                   float* __restrict__ sarr,
                                                   float* __restrict__ darr,
                                                   int M) {
  int nPanels = (M + 127) >> 7;
  int lin = blockIdx.y * 4 + blockIdx.x;
  int xcd = lin & 7;
  int t = lin >> 3;
  int bn_i = t & 3;
  int p = t >> 2;
  int bm_i = p * 8 + xcd;
  if (bm_i >= nPanels) return;
  int bm = bm_i * 128, bn = bn_i * 128;

  __shared__ u16 As[2][128 * 32];   // 8 KB each
  __shared__ u16 Bs[2][128 * 32];
  int tid = threadIdx.x;
  int lane = tid & 63, w = tid >> 6;
  int wr = w >> 1, wc = w & 1;

  // stage one BK=32 slice into buffer `buf`; swizzle mask m(row)=(row+(row>>2))&3
  // (full 32-bank coverage per 8 rows on the b128 read side; 2-way only = free)
  auto stage = [&](int buf, int k0) {
    #pragma unroll
    for (int it = 0; it < 2; it++) {
      int g = it * 256 + tid;          // 512 granules of 16B per matrix
      int row = g >> 2;
      int gb = g & 3;
      int gs = gb ^ ((row + (row >> 2)) & 3);
      int ar = bm + row; if (ar >= M) ar = M - 1;
      gload_lds16(A + (size_t)ar * HCW + k0 + gs * 8, &As[buf][g * 8]);
      gload_lds16(Bt + (size_t)(bn + row) * HCW + k0 + gs * 8, &Bs[buf][g * 8]);
    }
  };

  f32x4 acc[4][4] = {};
  stage(0, 0);
  for (int kb = 0; kb < 16; kb++) {
    __syncthreads();                       // buf[kb&1] ready (compiler drains vmcnt before barrier)
    if (kb < 15) stage((kb + 1) & 1, (kb + 1) * 32);
    int cb = kb & 1;
    bf16x8 af[4], bfr[4];
    #pragma unroll
    for (int f = 0; f < 4; f++) {
      int rowA = wr * 64 + f * 16 + (lane & 15);
      int gA = (lane >> 4) ^ ((rowA + (rowA >> 2)) & 3);
      af[f] = *(const bf16x8*)&As[cb][rowA * 32 + gA * 8];
      int rowB = wc * 64 + f * 16 + (lane & 15);
      int gB = (lane >> 4) ^ ((rowB + (rowB >> 2)) & 3);
      bfr[f] = *(const bf16x8*)&Bs[cb][rowB * 32 + gB * 8];
    }
    #pragma unroll
    for (int i = 0; i < 4; i++)
      #pragma unroll
      for (int j = 0; j < 4; j++)
        acc[i][j] = __builtin_amdgcn_mfma_f32_16x16x32_bf16(af[i], bfr[j], acc[i][j], 0, 0, 0);
  }

  int gr_base = bm + wr * 64;
  int gc_base = bn + wc * 64;
  #pragma unroll
  for (int i = 0; i < 4; i++) {
    #pragma unroll
    for (int j = 0; j < 4; j++) {
      int col = gc_base + j * 16 + (lane & 15);
      #pragma unroll
      for (int r = 0; r < 4; r++) {
        int rowg = gr_base + i * 16 + (lane >> 4) * 4 + r;
        if (rowg < M) C[(size_t)rowg * HCW + col] = f2bf(acc[i][j][r]);
      }
    }
  }
  // fused s/d: this wave's 64 cols == head (bn>>6)+wc
  int head = (bn >> 6) + wc;
  float asv[4], adv[4];
  #pragma unroll
  for (int j = 0; j < 4; j++) {
    asv[j] = a_src[head * 64 + j * 16 + (lane & 15)];
    adv[j] = a_dst[head * 64 + j * 16 + (lane & 15)];
  }
  #pragma unroll
  for (int i = 0; i < 4; i++) {
    #pragma unroll
    for (int r = 0; r < 4; r++) {
      float sv = acc[i][0][r] * asv[0] + acc[i][1][r] * asv[1]
               + acc[i][2][r] * asv[2] + acc[i][3][r] * asv[3];
      float dv = acc[i][0][r] * adv[0] + acc[i][1][r] * adv[1]
               + acc[i][2][r] * adv[2] + acc[i][3][r] * adv[3];
      sv += __shfl_xor(sv, 1); dv += __shfl_xor(dv, 1);
      sv += __shfl_xor(sv, 2); dv += __shfl_xor(dv, 2);
      sv += __shfl_xor(sv, 4); dv += __shfl_xor(dv, 4);
      sv += __shfl_xor(sv, 8); dv += __shfl_xor(dv, 8);
      if ((lane & 15) == 0) {
        int rowg = gr_base + i * 16 + (lane >> 4) * 4 + r;
        if (rowg < M) {
          sarr[(size_t)rowg * NHD + head] = sv;
          darr[(size_t)rowg * NHD + head] = dv;
        }
      }
    }
  }
}

// ---------------- channel-sliced softmax+agg (agg10, r12 best): 8 nodes/wave ----------------
__global__ __launch_bounds__(256) void k_agg10(const int* __restrict__ beg_, const int* __restrict__ deg_,
                                               const int* __restrict__ csr_src,
                                               const u16* __restrict__ hp, const float* __restrict__ s,
                                               const float* __restrict__ d, const float* __restrict__ bias,
                                               u16* __restrict__ hout, int N) {
  int hd = blockIdx.x;
  int wv = threadIdx.x >> 6, lane = threadIdx.x & 63;
  int nslot = lane >> 3;
  int q = lane & 7;
  int c = hd * 64 + q * 8;
  int n = blockIdx.y * 32 + wv * 8 + nslot;
  if (n >= N) return;
  int beg = beg_[n], end = beg + deg_[n];
  float dn = d[(size_t)n * NHD + hd];
  const u16* hpc = hp + c;
  float acc[8] = {0.f, 0.f, 0.f, 0.f, 0.f, 0.f, 0.f, 0.f};
  float den = 0.f;

  int i = beg;
  for (; i + 2 <= end; i += 2) {
    int s0 = csr_src[i], s1 = csr_src[i + 1];
    float e0 = s[(size_t)s0 * NHD + hd] + dn;
    float e1 = s[(size_t)s1 * NHD + hd] + dn;
    uint4 v0 = *(const uint4*)(hpc + (size_t)s0 * HCW);
    uint4 v1 = *(const uint4*)(hpc + (size_t)s1 * HCW);
    e0 = (e0 > 0.f) ? e0 : 0.2f * e0;
    e1 = (e1 > 0.f) ? e1 : 0.2f * e1;
    float x0 = __expf(e0), x1 = __expf(e1);
    den += x0 + x1;
    u32 w0[4] = {v0.x, v0.y, v0.z, v0.w};
    u32 w1[4] = {v1.x, v1.y, v1.z, v1.w};
    #pragma unroll
    for (int j = 0; j < 4; j++) {
      acc[2 * j]     += x0 * bf2f(w0[j] & 0xffff) + x1 * bf2f(w1[j] & 0xffff);
      acc[2 * j + 1] += x0 * bf2f(w0[j] >> 16)    + x1 * bf2f(w1[j] >> 16);
    }
  }
  if (i < end) {
    int s0 = csr_src[i];
    float e0 = s[(size_t)s0 * NHD + hd] + dn;
    uint4 v0 = *(const uint4*)(hpc + (size_t)s0 * HCW);
    e0 = (e0 > 0.f) ? e0 : 0.2f * e0;
    float x0 = __expf(e0);
    den += x0;
    u32 w0[4] = {v0.x, v0.y, v0.z, v0.w};
    #pragma unroll
    for (int j = 0; j < 4; j++) {
      acc[2 * j]     += x0 * bf2f(w0[j] & 0xffff);
      acc[2 * j + 1] += x0 * bf2f(w0[j] >> 16);
    }
  }

  float inv = 1.f / (den + 1e-16f);
  float4 bv0 = *(const float4*)(bias + c);
  float4 bv1 = *(const float4*)(bias + c + 4);
  float bb[8] = {bv0.x, bv0.y, bv0.z, bv0.w, bv1.x, bv1.y, bv1.z, bv1.w};
  u32 out[4];
  #pragma unroll
  for (int j = 0; j < 4; j++) {
    float o0 = fmaxf(acc[2 * j] * inv + bb[2 * j], 0.f);
    float o1 = fmaxf(acc[2 * j + 1] * inv + bb[2 * j + 1], 0.f);
    out[j] = (u32)f2bf(o0) | ((u32)f2bf(o1) << 16);
  }
  *(uint4*)(hout + (size_t)n * HCW + c) = make_uint4(out[0], out[1], out[2], out[3]);
}

// ---------------- fused final heads via MFMA: [M,512] @ Wf^T[512,80] ----------------
__global__ __launch_bounds__(256) void k_final2(const u16* __restrict__ A,
                                                const u16* __restrict__ Wf,
                                                const float* __restrict__ b_att,
                                                const float* __restrict__ b_h1,
                                                const float* __restrict__ W_h2,
                                                const float* __restrict__ b_h2,
                                                float* __restrict__ anomaly, float* __restrict__ attw,
                                                int M) {
  __shared__ u16 As[128 * 64];
  __shared__ u16 Bs[80 * 64];
  __shared__ float so[4][32][84];
  int tid = threadIdx.x;
  int lane = tid & 63, w = tid >> 6;
  int bm = blockIdx.x * 128;
  f32x4 acc[2][5] = {};
  for (int k0 = 0; k0 < 512; k0 += 64) {
    __syncthreads();
    #pragma unroll
    for (int it = 0; it < 7; it++) {
      int g = it * 256 + tid;
      if (g < 1024) {
        int row = g >> 3, gb = g & 7;
        int gs = gb ^ (row & 7);
        int ar = bm + row; if (ar >= M) ar = M - 1;
        gload_lds16(A + (size_t)ar * HCW + k0 + gs * 8, &As[g * 8]);
      } else if (g < 1664) {
        int gg = g - 1024;
        int row = gg >> 3, gb = gg & 7;
        int gs = gb ^ (row & 7);
        gload_lds16(Wf + (size_t)row * 512 + k0 + gs * 8, &Bs[gg * 8]);
      }
    }
    __syncthreads();
    #pragma unroll
    for (int ks = 0; ks < 2; ks++) {
      bf16x8 af[2], bfr[5];
      #pragma unroll
      for (int i = 0; i < 2; i++) {
        int rowA = w * 32 + i * 16 + (lane & 15);
        int gA = ((ks * 4 + (lane >> 4)) ^ (rowA & 7));
        af[i] = *(const bf16x8*)&As[rowA * 64 + gA * 8];
      }
      #pragma unroll
      for (int j = 0; j < 5; j++) {
        int rowB = j * 16 + (lane & 15);
        int gB = ((ks * 4 + (lane >> 4)) ^ (rowB & 7));
        bfr[j] = *(const bf16x8*)&Bs[rowB * 64 + gB * 8];
      }
      #pragma unroll
      for (int i = 0; i < 2; i++)
        #pragma unroll
        for (int j = 0; j < 5; j++)
          acc[i][j] = __builtin_amdgcn_mfma_f32_16x16x32_bf16(af[i], bfr[j], acc[i][j], 0, 0, 0);
    }
  }
  #pragma unroll
  for (int i = 0; i < 2; i++) {
    #pragma unroll
    for (int j = 0; j < 5; j++) {
      int col = j * 16 + (lane & 15);
      #pragma unroll
      for (int r = 0; r < 4; r++) {
        int row_l = i * 16 + (lane >> 4) * 4 + r;
        so[w][row_l][col] = acc[i][j][r];
      }
    }
  }
  int row_l = lane >> 1, half = lane & 1;
  int n = bm + w * 32 + row_l;
  if (n < M) {
    float hacc = 0.f;
    #pragma unroll
    for (int kk = 0; kk < 32; kk++) {
      int cc = half * 32 + kk;
      float v = fmaxf(so[w][row_l][cc] + b_h1[cc], 0.f);
      hacc += v * W_h2[cc];
    }
    hacc += __shfl_xor(hacc, 1);
    if (half == 0) {
      anomaly[n] = 1.f / (1.f + __expf(-(hacc + b_h2[0])));
    } else {
      float lg[8];
      float mx = -1e30f;
      #pragma unroll
      for (int j = 0; j < 8; j++) {
        lg[j] = so[w][row_l][64 + j] + b_att[j];
        mx = fmaxf(mx, lg[j]);
      }
      float sum = 0.f;
      #pragma unroll
      for (int j = 0; j < 8; j++) { lg[j] = __expf(lg[j] - mx); sum += lg[j]; }
      float inv = 1.f / sum;
      #pragma unroll
      for (int j = 0; j < 8; j++) attw[(size_t)n * 8 + j] = lg[j] * inv;
    }
  }
}

extern "C" void kernel_launch(void* const* d_in, const int* in_sizes, int n_in,
                              void* d_out, int out_size, void* d_ws, size_t ws_size,
                              hipStream_t stream) {
  const float* x       = (const float*)d_in[0];
  const int*   ei      = (const int*)d_in[1];
  const float* W_in    = (const float*)d_in[2];
  const float* b_in    = (const float*)d_in[3];
  const float* W_gat   = (const float*)d_in[4];
  const float* att_src = (const float*)d_in[5];
  const float* att_dst = (const float*)d_in[6];
  const float* b_gat   = (const float*)d_in[7];
  const float* W_att   = (const float*)d_in[8];
  const float* b_att   = (const float*)d_in[9];
  const float* W_h1    = (const float*)d_in[10];
  const float* b_h1    = (const float*)d_in[11];
  const float* W_h2    = (const float*)d_in[12];
  const float* b_h2    = (const float*)d_in[13];

  const int N  = in_sizes[0] / 32;
  const int E  = in_sizes[1] / 2;
  const int ET = E + N;

  char* ws = (char*)d_ws;
  size_t off = 0;
  auto alloc = [&](size_t bytes) -> void* {
    void* p = ws + off;
    off = (off + bytes + 255) & ~(size_t)255;
    return p;
  };
  u16* h     = (u16*)alloc((size_t)N * HCW * 2);
  u16* hp    = (u16*)alloc((size_t)N * HCW * 2);
  u16* Wt    = (u16*)alloc((size_t)3 * HCW * HCW * 2);
  u16* Wf    = (u16*)alloc((size_t)80 * 512 * 2);
  u16* xb    = (u16*)alloc((size_t)N * 32 * 2);
  u16* Wtin  = (u16*)alloc((size_t)512 * 32 * 2);
  float* sarr = (float*)alloc((size_t)N * NHD * 4);
  float* darr = (float*)alloc((size_t)N * NHD * 4);
  int* zbuf   = (int*)alloc((size_t)(2 * N + 64) * 4);
  int* deg    = zbuf;
  int* cnt    = zbuf + N;
  int* cursor = zbuf + 2 * N;
  int* beg    = (int*)alloc((size_t)N * 4);
  int* csr    = (int*)alloc((size_t)ET * 4);

  float* anomaly = (float*)d_out;
  float* attw    = (float*)d_out + N;

  hipMemsetAsync(zbuf, 0, (size_t)(2 * N + 1) * 4, stream);

  int gbE = (ET + 255) / 256;
  int nb  = (N + 255) / 256;
  k_hist<<<gbE, 256, 0, stream>>>(ei, deg, E, N);
  k_alloc<<<nb, 256, 0, stream>>>(deg, beg, cursor, N);
  k_fill<<<gbE, 256, 0, stream>>>(ei, beg, cnt, csr, E, N);

  int xtotal = N * 32;
  int XB = (xtotal / 8 + 255) / 256;
  k_prep<<<848 + XB + 64, 256, 0, stream>>>(W_gat, Wt, W_h1, W_att, Wf, x, xb, xtotal,
                                            W_in, Wtin, XB);
  k_inproj3<<<dim3(4, (N + 127) / 128), 256, 0, stream>>>(xb, Wtin, b_in, h, N);

  int nPanels = (N + 127) / 128;
  int nPanelsPad = ((nPanels + 7) / 8) * 8;
  dim3 ggrid(4, nPanelsPad);
  dim3 agrid(8, (N + 31) / 32);
  for (int l = 0; l < 3; l++) {
    k_gemm_mfma<<<ggrid, 256, 0, stream>>>(h, Wt + (size_t)l * HCW * HCW, hp,
                                           att_src + (size_t)l * NHD * CCH,
                                           att_dst + (size_t)l * NHD * CCH,
                                           sarr, darr, N);
    k_agg10<<<agrid, 256, 0, stream>>>(beg, deg, csr, hp, sarr, darr,
                                       b_gat + (size_t)l * HCW, h, N);
  }

  k_final2<<<(N + 127) / 128, 256, 0, stream>>>(h, Wf, b_att, b_h1, W_h2, b_h2,
                                                anomaly, attw, N);
}

// Round 16
// 413.852 us; speedup vs baseline: 1.4442x; 1.0250x over previous
//
#include <hip/hip_runtime.h>
#include <hip/hip_bf16.h>
#include <math.h>

#define HCW 512   // concat width H*C
#define NHD 8     // heads
#define CCH 64    // per-head channels

typedef unsigned short u16;
typedef unsigned int   u32;
typedef __attribute__((ext_vector_type(8))) short bf16x8;
typedef __attribute__((ext_vector_type(4))) float f32x4;

__device__ __forceinline__ float bf2f(u32 u) {
  union { float f; u32 i; } v; v.i = u << 16; return v.f;
}
__device__ __forceinline__ u16 f2bf(float f) {
  u32 x = __builtin_bit_cast(u32, f);
  return (u16)((x + 0x7fff + ((x >> 16) & 1)) >> 16);
}
__device__ __forceinline__ void gload_lds16(const void* g, void* l) {
  __builtin_amdgcn_global_load_lds(
      (const __attribute__((address_space(1))) u32*)g,
      (__attribute__((address_space(3))) u32*)l, 16, 0, 0);
}

// ---------------- CSR build (by dst), atomic-alloc ----------------
__global__ void k_hist(const int* __restrict__ ei, int* __restrict__ deg, int E, int N) {
  int e = blockIdx.x * blockDim.x + threadIdx.x;
  if (e >= E + N) return;
  int dst = (e < E) ? ei[E + e] : (e - E);
  atomicAdd(&deg[dst], 1);
}

__global__ __launch_bounds__(256) void k_alloc(const int* __restrict__ deg, int* __restrict__ beg,
                                               int* __restrict__ cursor, int N) {
  int n = blockIdx.x * 256 + threadIdx.x;
  int lane = threadIdx.x & 63;
  int v = (n < N) ? deg[n] : 0;
  int incl = v;
  #pragma unroll
  for (int off = 1; off < 64; off <<= 1) {
    int t = __shfl_up(incl, off);
    if (lane >= off) incl += t;
  }
  int total = __shfl(incl, 63);
  int base = 0;
  if (lane == 63) base = atomicAdd(cursor, total);
  base = __shfl(base, 63);
  if (n < N) beg[n] = base + incl - v;
}

__global__ void k_fill(const int* __restrict__ ei, const int* __restrict__ beg,
                       int* __restrict__ cnt, int* __restrict__ csr_src, int E, int N) {
  int e = blockIdx.x * blockDim.x + threadIdx.x;
  if (e >= E + N) return;
  int src, dst;
  if (e < E) { src = ei[e]; dst = ei[E + e]; } else { src = e - E; dst = e - E; }
  int pos = beg[dst] + atomicAdd(&cnt[dst], 1);
  csr_src[pos] = src;
}

// ---------------- fused prep: W_gat^T, Wf, x->bf16, W_in^T ----------------
__global__ __launch_bounds__(256) void k_prep(const float* __restrict__ W_gat, u16* __restrict__ Wt,
                                              const float* __restrict__ W_h1, const float* __restrict__ W_att,
                                              u16* __restrict__ Wf,
                                              const float* __restrict__ x, u16* __restrict__ xb, int xtotal,
                                              const float* __restrict__ W_in, u16* __restrict__ Wtin,
                                              int XB) {
  __shared__ float sm[32][33];
  int b = blockIdx.x;
  int t = threadIdx.x;
  if (b < 768) {
    int l = b >> 8, rem = b & 255;
    int n0 = (rem & 15) * 32, k0 = (rem >> 4) * 32;
    const float* Wl = W_gat + (size_t)l * HCW * HCW;
    u16* Wtl = Wt + (size_t)l * HCW * HCW;
    int tx = t & 31, ty = t >> 5;
    #pragma unroll
    for (int r = 0; r < 32; r += 8)
      sm[ty + r][tx] = Wl[(size_t)(k0 + ty + r) * HCW + n0 + tx];
    __syncthreads();
    #pragma unroll
    for (int r = 0; r < 32; r += 8)
      Wtl[(size_t)(n0 + ty + r) * HCW + k0 + tx] = f2bf(sm[tx][ty + r]);
  } else if (b < 848) {
    int n = b - 768;
    for (int k = t; k < 512; k += 256) {
      float v = 0.f;
      if (n < 64) v = W_h1[(size_t)k * 64 + n];
      else if (n < 72) v = W_att[(size_t)k * 8 + (n - 64)];
      Wf[(size_t)n * 512 + k] = f2bf(v);
    }
  } else if (b < 848 + XB) {
    int i = ((b - 848) * 256 + t) * 8;
    if (i < xtotal) {
      float4 a = *(const float4*)(x + i);
      float4 bb = *(const float4*)(x + i + 4);
      uint4 o;
      o.x = (u32)f2bf(a.x) | ((u32)f2bf(a.y) << 16);
      o.y = (u32)f2bf(a.z) | ((u32)f2bf(a.w) << 16);
      o.z = (u32)f2bf(bb.x) | ((u32)f2bf(bb.y) << 16);
      o.w = (u32)f2bf(bb.z) | ((u32)f2bf(bb.w) << 16);
      *(uint4*)(xb + i) = o;
    }
  } else {
    int idx = (b - 848 - XB) * 256 + t;
    int n = idx >> 5, k = idx & 31;
    Wtin[idx] = f2bf(W_in[(size_t)k * HCW + n]);
  }
}

// ---------------- input projection via MFMA ----------------
__global__ __launch_bounds__(256) void k_inproj3(const u16* __restrict__ xb, const u16* __restrict__ Wt,
                                                 const float* __restrict__ b, u16* __restrict__ h, int N) {
  __shared__ u16 As[128 * 32];
  __shared__ u16 Bs[128 * 32];
  int tid = threadIdx.x, lane = tid & 63, w = tid >> 6;
  int bm = blockIdx.y * 128, bn = blockIdx.x * 128;
  #pragma unroll
  for (int it = 0; it < 4; it++) {
    int g = it * 256 + tid;
    if (g < 512) {
      int row = g >> 2, gb = g & 3, gs = gb ^ (row & 3);
      int ar = bm + row; if (ar >= N) ar = N - 1;
      gload_lds16(xb + (size_t)ar * 32 + gs * 8, &As[g * 8]);
    } else {
      int gg = g - 512;
      int row = gg >> 2, gb = gg & 3, gs = gb ^ (row & 3);
      gload_lds16(Wt + (size_t)(bn + row) * 32 + gs * 8, &Bs[gg * 8]);
    }
  }
  __syncthreads();
  bf16x8 af[2];
  #pragma unroll
  for (int i = 0; i < 2; i++) {
    int rowA = w * 32 + i * 16 + (lane & 15);
    int gA = (lane >> 4) ^ (rowA & 3);
    af[i] = *(const bf16x8*)&As[rowA * 32 + gA * 8];
  }
  f32x4 acc[2][8] = {};
  #pragma unroll
  for (int j = 0; j < 8; j++) {
    int rowB = j * 16 + (lane & 15);
    int gB = (lane >> 4) ^ (rowB & 3);
    bf16x8 bfr = *(const bf16x8*)&Bs[rowB * 32 + gB * 8];
    #pragma unroll
    for (int i = 0; i < 2; i++)
      acc[i][j] = __builtin_amdgcn_mfma_f32_16x16x32_bf16(af[i], bfr, acc[i][j], 0, 0, 0);
  }
  #pragma unroll
  for (int j = 0; j < 8; j++) {
    int col = bn + j * 16 + (lane & 15);
    float bb = b[col];
    #pragma unroll
    for (int i = 0; i < 2; i++) {
      #pragma unroll
      for (int r = 0; r < 4; r++) {
        int n = bm + w * 32 + i * 16 + (lane >> 4) * 4 + r;
        if (n < N) h[(size_t)n * HCW + col] = f2bf(fmaxf(acc[i][j][r] + bb, 0.f));
      }
    }
  }
}

// ---------------- bf16 MFMA GEMM + fused s/d epilogue, XCD-panel swizzle (r12 best) ----------------
__global__ __launch_bounds__(256) void k_gemm_mfma(const u16* __restrict__ A,
                                                   const u16* __restrict__ Bt,
                                                   u16* __restrict__ C,
                                                   const float* __restrict__ a_src,
                                                   const float* __restrict__ a_dst,
                                                   float* __restrict__ sarr,
                                                   float* __restrict__ darr,
                                                   int M) {
  int nPanels = (M + 127) >> 7;
  int lin = blockIdx.y * 4 + blockIdx.x;
  int xcd = lin & 7;
  int t = lin >> 3;
  int bn_i = t & 3;
  int p = t >> 2;
  int bm_i = p * 8 + xcd;
  if (bm_i >= nPanels) return;
  int bm = bm_i * 128, bn = bn_i * 128;

  __shared__ u16 As[128 * 64];
  __shared__ u16 Bs[128 * 64];
  int tid = threadIdx.x;
  int lane = tid & 63, w = tid >> 6;
  int wr = w >> 1, wc = w & 1;
  f32x4 acc[4][4] = {};
  for (int k0 = 0; k0 < 512; k0 += 64) {
    __syncthreads();
    #pragma unroll
    for (int it = 0; it < 4; it++) {
      int g = it * 256 + tid;
      int row = g >> 3;
      int gb = g & 7;
      int gs = gb ^ (row & 7);
      int ar = bm + row; if (ar >= M) ar = M - 1;
      gload_lds16(A + (size_t)ar * HCW + k0 + gs * 8, &As[g * 8]);
      gload_lds16(Bt + (size_t)(bn + row) * HCW + k0 + gs * 8, &Bs[g * 8]);
    }
    __syncthreads();
    #pragma unroll
    for (int ks = 0; ks < 2; ks++) {
      bf16x8 af[4], bfr[4];
      #pragma unroll
      for (int f = 0; f < 4; f++) {
        int rowA = wr * 64 + f * 16 + (lane & 15);
        int gA = ((ks * 4 + (lane >> 4)) ^ (rowA & 7));
        af[f] = *(const bf16x8*)&As[rowA * 64 + gA * 8];
        int rowB = wc * 64 + f * 16 + (lane & 15);
        int gB = ((ks * 4 + (lane >> 4)) ^ (rowB & 7));
        bfr[f] = *(const bf16x8*)&Bs[rowB * 64 + gB * 8];
      }
      #pragma unroll
      for (int i = 0; i < 4; i++)
        #pragma unroll
        for (int j = 0; j < 4; j++)
          acc[i][j] = __builtin_amdgcn_mfma_f32_16x16x32_bf16(af[i], bfr[j], acc[i][j], 0, 0, 0);
    }
  }
  int gr_base = bm + wr * 64;
  int gc_base = bn + wc * 64;
  #pragma unroll
  for (int i = 0; i < 4; i++) {
    #pragma unroll
    for (int j = 0; j < 4; j++) {
      int col = gc_base + j * 16 + (lane & 15);
      #pragma unroll
      for (int r = 0; r < 4; r++) {
        int rowg = gr_base + i * 16 + (lane >> 4) * 4 + r;
        if (rowg < M) C[(size_t)rowg * HCW + col] = f2bf(acc[i][j][r]);
      }
    }
  }
  int head = (bn >> 6) + wc;
  float asv[4], adv[4];
  #pragma unroll
  for (int j = 0; j < 4; j++) {
    asv[j] = a_src[head * 64 + j * 16 + (lane & 15)];
    adv[j] = a_dst[head * 64 + j * 16 + (lane & 15)];
  }
  #pragma unroll
  for (int i = 0; i < 4; i++) {
    #pragma unroll
    for (int r = 0; r < 4; r++) {
      float sv = acc[i][0][r] * asv[0] + acc[i][1][r] * asv[1]
               + acc[i][2][r] * asv[2] + acc[i][3][r] * asv[3];
      float dv = acc[i][0][r] * adv[0] + acc[i][1][r] * adv[1]
               + acc[i][2][r] * adv[2] + acc[i][3][r] * adv[3];
      sv += __shfl_xor(sv, 1); dv += __shfl_xor(dv, 1);
      sv += __shfl_xor(sv, 2); dv += __shfl_xor(dv, 2);
      sv += __shfl_xor(sv, 4); dv += __shfl_xor(dv, 4);
      sv += __shfl_xor(sv, 8); dv += __shfl_xor(dv, 8);
      if ((lane & 15) == 0) {
        int rowg = gr_base + i * 16 + (lane >> 4) * 4 + r;
        if (rowg < M) {
          sarr[(size_t)rowg * NHD + head] = sv;
          darr[(size_t)rowg * NHD + head] = dv;
        }
      }
    }
  }
}

// ---------------- channel-sliced softmax+agg (agg10, r12 best): 8 nodes/wave ----------------
__global__ __launch_bounds__(256) void k_agg10(const int* __restrict__ beg_, const int* __restrict__ deg_,
                                               const int* __restrict__ csr_src,
                                               const u16* __restrict__ hp, const float* __restrict__ s,
                                               const float* __restrict__ d, const float* __restrict__ bias,
                                               u16* __restrict__ hout, int N) {
  int hd = blockIdx.x;
  int wv = threadIdx.x >> 6, lane = threadIdx.x & 63;
  int nslot = lane >> 3;
  int q = lane & 7;
  int c = hd * 64 + q * 8;
  int n = blockIdx.y * 32 + wv * 8 + nslot;
  if (n >= N) return;
  int beg = beg_[n], end = beg + deg_[n];
  float dn = d[(size_t)n * NHD + hd];
  const u16* hpc = hp + c;
  float acc[8] = {0.f, 0.f, 0.f, 0.f, 0.f, 0.f, 0.f, 0.f};
  float den = 0.f;

  int i = beg;
  for (; i + 2 <= end; i += 2) {
    int s0 = csr_src[i], s1 = csr_src[i + 1];
    float e0 = s[(size_t)s0 * NHD + hd] + dn;
    float e1 = s[(size_t)s1 * NHD + hd] + dn;
    uint4 v0 = *(const uint4*)(hpc + (size_t)s0 * HCW);
    uint4 v1 = *(const uint4*)(hpc + (size_t)s1 * HCW);
    e0 = (e0 > 0.f) ? e0 : 0.2f * e0;
    e1 = (e1 > 0.f) ? e1 : 0.2f * e1;
    float x0 = __expf(e0), x1 = __expf(e1);
    den += x0 + x1;
    u32 w0[4] = {v0.x, v0.y, v0.z, v0.w};
    u32 w1[4] = {v1.x, v1.y, v1.z, v1.w};
    #pragma unroll
    for (int j = 0; j < 4; j++) {
      acc[2 * j]     += x0 * bf2f(w0[j] & 0xffff) + x1 * bf2f(w1[j] & 0xffff);
      acc[2 * j + 1] += x0 * bf2f(w0[j] >> 16)    + x1 * bf2f(w1[j] >> 16);
    }
  }
  if (i < end) {
    int s0 = csr_src[i];
    float e0 = s[(size_t)s0 * NHD + hd] + dn;
    uint4 v0 = *(const uint4*)(hpc + (size_t)s0 * HCW);
    e0 = (e0 > 0.f) ? e0 : 0.2f * e0;
    float x0 = __expf(e0);
    den += x0;
    u32 w0[4] = {v0.x, v0.y, v0.z, v0.w};
    #pragma unroll
    for (int j = 0; j < 4; j++) {
      acc[2 * j]     += x0 * bf2f(w0[j] & 0xffff);
      acc[2 * j + 1] += x0 * bf2f(w0[j] >> 16);
    }
  }

  float inv = 1.f / (den + 1e-16f);
  float4 bv0 = *(const float4*)(bias + c);
  float4 bv1 = *(const float4*)(bias + c + 4);
  float bb[8] = {bv0.x, bv0.y, bv0.z, bv0.w, bv1.x, bv1.y, bv1.z, bv1.w};
  u32 out[4];
  #pragma unroll
  for (int j = 0; j < 4; j++) {
    float o0 = fmaxf(acc[2 * j] * inv + bb[2 * j], 0.f);
    float o1 = fmaxf(acc[2 * j + 1] * inv + bb[2 * j + 1], 0.f);
    out[j] = (u32)f2bf(o0) | ((u32)f2bf(o1) << 16);
  }
  *(uint4*)(hout + (size_t)n * HCW + c) = make_uint4(out[0], out[1], out[2], out[3]);
}

// ---------------- fused final heads via MFMA: [M,512] @ Wf^T[512,80] ----------------
__global__ __launch_bounds__(256) void k_final2(const u16* __restrict__ A,
                                                const u16* __restrict__ Wf,
                                                const float* __restrict__ b_att,
                                                const float* __restrict__ b_h1,
                                                const float* __restrict__ W_h2,
                                                const float* __restrict__ b_h2,
                                                float* __restrict__ anomaly, float* __restrict__ attw,
                                                int M) {
  __shared__ u16 As[128 * 64];
  __shared__ u16 Bs[80 * 64];
  __shared__ float so[4][32][84];
  int tid = threadIdx.x;
  int lane = tid & 63, w = tid >> 6;
  int bm = blockIdx.x * 128;
  f32x4 acc[2][5] = {};
  for (int k0 = 0; k0 < 512; k0 += 64) {
    __syncthreads();
    #pragma unroll
    for (int it = 0; it < 7; it++) {
      int g = it * 256 + tid;
      if (g < 1024) {
        int row = g >> 3, gb = g & 7;
        int gs = gb ^ (row & 7);
        int ar = bm + row; if (ar >= M) ar = M - 1;
        gload_lds16(A + (size_t)ar * HCW + k0 + gs * 8, &As[g * 8]);
      } else if (g < 1664) {
        int gg = g - 1024;
        int row = gg >> 3, gb = gg & 7;
        int gs = gb ^ (row & 7);
        gload_lds16(Wf + (size_t)row * 512 + k0 + gs * 8, &Bs[gg * 8]);
      }
    }
    __syncthreads();
    #pragma unroll
    for (int ks = 0; ks < 2; ks++) {
      bf16x8 af[2], bfr[5];
      #pragma unroll
      for (int i = 0; i < 2; i++) {
        int rowA = w * 32 + i * 16 + (lane & 15);
        int gA = ((ks * 4 + (lane >> 4)) ^ (rowA & 7));
        af[i] = *(const bf16x8*)&As[rowA * 64 + gA * 8];
      }
      #pragma unroll
      for (int j = 0; j < 5; j++) {
        int rowB = j * 16 + (lane & 15);
        int gB = ((ks * 4 + (lane >> 4)) ^ (rowB & 7));
        bfr[j] = *(const bf16x8*)&Bs[rowB * 64 + gB * 8];
      }
      #pragma unroll
      for (int i = 0; i < 2; i++)
        #pragma unroll
        for (int j = 0; j < 5; j++)
          acc[i][j] = __builtin_amdgcn_mfma_f32_16x16x32_bf16(af[i], bfr[j], acc[i][j], 0, 0, 0);
    }
  }
  #pragma unroll
  for (int i = 0; i < 2; i++) {
    #pragma unroll
    for (int j = 0; j < 5; j++) {
      int col = j * 16 + (lane & 15);
      #pragma unroll
      for (int r = 0; r < 4; r++) {
        int row_l = i * 16 + (lane >> 4) * 4 + r;
        so[w][row_l][col] = acc[i][j][r];
      }
    }
  }
  int row_l = lane >> 1, half = lane & 1;
  int n = bm + w * 32 + row_l;
  if (n < M) {
    float hacc = 0.f;
    #pragma unroll
    for (int kk = 0; kk < 32; kk++) {
      int cc = half * 32 + kk;
      float v = fmaxf(so[w][row_l][cc] + b_h1[cc], 0.f);
      hacc += v * W_h2[cc];
    }
    hacc += __shfl_xor(hacc, 1);
    if (half == 0) {
      anomaly[n] = 1.f / (1.f + __expf(-(hacc + b_h2[0])));
    } else {
      float lg[8];
      float mx = -1e30f;
      #pragma unroll
      for (int j = 0; j < 8; j++) {
        lg[j] = so[w][row_l][64 + j] + b_att[j];
        mx = fmaxf(mx, lg[j]);
      }
      float sum = 0.f;
      #pragma unroll
      for (int j = 0; j < 8; j++) { lg[j] = __expf(lg[j] - mx); sum += lg[j]; }
      float inv = 1.f / sum;
      #pragma unroll
      for (int j = 0; j < 8; j++) attw[(size_t)n * 8 + j] = lg[j] * inv;
    }
  }
}

extern "C" void kernel_launch(void* const* d_in, const int* in_sizes, int n_in,
                              void* d_out, int out_size, void* d_ws, size_t ws_size,
                              hipStream_t stream) {
  const float* x       = (const float*)d_in[0];
  const int*   ei      = (const int*)d_in[1];
  const float* W_in    = (const float*)d_in[2];
  const float* b_in    = (const float*)d_in[3];
  const float* W_gat   = (const float*)d_in[4];
  const float* att_src = (const float*)d_in[5];
  const float* att_dst = (const float*)d_in[6];
  const float* b_gat   = (const float*)d_in[7];
  const float* W_att   = (const float*)d_in[8];
  const float* b_att   = (const float*)d_in[9];
  const float* W_h1    = (const float*)d_in[10];
  const float* b_h1    = (const float*)d_in[11];
  const float* W_h2    = (const float*)d_in[12];
  const float* b_h2    = (const float*)d_in[13];

  const int N  = in_sizes[0] / 32;
  const int E  = in_sizes[1] / 2;
  const int ET = E + N;

  char* ws = (char*)d_ws;
  size_t off = 0;
  auto alloc = [&](size_t bytes) -> void* {
    void* p = ws + off;
    off = (off + bytes + 255) & ~(size_t)255;
    return p;
  };
  u16* h     = (u16*)alloc((size_t)N * HCW * 2);
  u16* hp    = (u16*)alloc((size_t)N * HCW * 2);
  u16* Wt    = (u16*)alloc((size_t)3 * HCW * HCW * 2);
  u16* Wf    = (u16*)alloc((size_t)80 * 512 * 2);
  u16* xb    = (u16*)alloc((size_t)N * 32 * 2);
  u16* Wtin  = (u16*)alloc((size_t)512 * 32 * 2);
  float* sarr = (float*)alloc((size_t)N * NHD * 4);
  float* darr = (float*)alloc((size_t)N * NHD * 4);
  int* zbuf   = (int*)alloc((size_t)(2 * N + 64) * 4);
  int* deg    = zbuf;
  int* cnt    = zbuf + N;
  int* cursor = zbuf + 2 * N;
  int* beg    = (int*)alloc((size_t)N * 4);
  int* csr    = (int*)alloc((size_t)ET * 4);

  float* anomaly = (float*)d_out;
  float* attw    = (float*)d_out + N;

  hipMemsetAsync(zbuf, 0, (size_t)(2 * N + 1) * 4, stream);

  int gbE = (ET + 255) / 256;
  int nb  = (N + 255) / 256;
  k_hist<<<gbE, 256, 0, stream>>>(ei, deg, E, N);
  k_alloc<<<nb, 256, 0, stream>>>(deg, beg, cursor, N);
  k_fill<<<gbE, 256, 0, stream>>>(ei, beg, cnt, csr, E, N);

  int xtotal = N * 32;
  int XB = (xtotal / 8 + 255) / 256;
  k_prep<<<848 + XB + 64, 256, 0, stream>>>(W_gat, Wt, W_h1, W_att, Wf, x, xb, xtotal,
                                            W_in, Wtin, XB);
  k_inproj3<<<dim3(4, (N + 127) / 128), 256, 0, stream>>>(xb, Wtin, b_in, h, N);

  int nPanels = (N + 127) / 128;
  int nPanelsPad = ((nPanels + 7) / 8) * 8;
  dim3 ggrid(4, nPanelsPad);
  dim3 agrid(8, (N + 31) / 32);
  for (int l = 0; l < 3; l++) {
    k_gemm_mfma<<<ggrid, 256, 0, stream>>>(h, Wt + (size_t)l * HCW * HCW, hp,
                                           att_src + (size_t)l * NHD * CCH,
                                           att_dst + (size_t)l * NHD * CCH,
                                           sarr, darr, N);
    k_agg10<<<agrid, 256, 0, stream>>>(beg, deg, csr, hp, sarr, darr,
                                       b_gat + (size_t)l * HCW, h, N);
  }

  k_final2<<<(N + 127) / 128, 256, 0, stream>>>(h, Wf, b_att, b_h1, W_h2, b_h2,
                                                anomaly, attw, N);
}